// Round 3
// baseline (1072.205 us; speedup 1.0000x reference)
//
#include <hip/hip_runtime.h>

#define N_P 100000
#define N_A 50000
#define DD  64
#define E_W 800000
#define E_C 1200000
#define E_TOT (E_W + E_C)

#define SCAN_TOT (2 * N_P)
#define SCAN_CHUNK 2048
#define NCH ((SCAN_TOT + SCAN_CHUNK - 1) / SCAN_CHUNK)  // 98

typedef unsigned int u32x4 __attribute__((ext_vector_type(4)));

// ---------------- K1: degree histograms (int atomics, int2 index loads) ------
__global__ __launch_bounds__(256) void k_degrees(
    const int* __restrict__ wsrc, const int* __restrict__ wdst,
    const int* __restrict__ csrc, const int* __restrict__ cdst,
    unsigned* __restrict__ deg_a, unsigned* __restrict__ deg_p,
    unsigned* __restrict__ cnt2) {
    int t = blockIdx.x * blockDim.x + threadIdx.x;
    int e = t * 2;
    if (e + 2 <= E_W) {
        int2 s = *reinterpret_cast<const int2*>(&wsrc[e]);
        int2 d = *reinterpret_cast<const int2*>(&wdst[e]);
        atomicAdd(&deg_a[s.x], 1u);
        atomicAdd(&deg_a[s.y], 1u);
        atomicAdd(&cnt2[d.x], 1u);
        atomicAdd(&cnt2[d.y], 1u);
    } else if (e < E_W) {
        atomicAdd(&deg_a[wsrc[e]], 1u);
        atomicAdd(&cnt2[wdst[e]], 1u);
    }
    if (e + 2 <= E_C) {
        int2 s = *reinterpret_cast<const int2*>(&csrc[e]);
        int2 d = *reinterpret_cast<const int2*>(&cdst[e]);
        atomicAdd(&deg_p[s.x], 1u);
        atomicAdd(&deg_p[s.y], 1u);
        atomicAdd(&cnt2[N_P + d.x], 1u);
        atomicAdd(&cnt2[N_P + d.y], 1u);
    } else if (e < E_C) {
        atomicAdd(&deg_p[csrc[e]], 1u);
        atomicAdd(&cnt2[N_P + cdst[e]], 1u);
    }
}

// ---------------- K2a: per-chunk local exclusive scan ----------------
__global__ __launch_bounds__(256) void k_scan_local(
    const unsigned* __restrict__ cnt2, unsigned* __restrict__ offs,
    unsigned* __restrict__ chunkSum) {
    __shared__ unsigned lds[256];
    const int b = blockIdx.x, t = threadIdx.x;
    const int base = b * SCAN_CHUNK + t * 8;
    unsigned v[8];
    unsigned s = 0;
    if (base + 8 <= SCAN_TOT) {
        uint4 a0 = *reinterpret_cast<const uint4*>(&cnt2[base]);
        uint4 a1 = *reinterpret_cast<const uint4*>(&cnt2[base + 4]);
        v[0] = a0.x; v[1] = a0.y; v[2] = a0.z; v[3] = a0.w;
        v[4] = a1.x; v[5] = a1.y; v[6] = a1.z; v[7] = a1.w;
#pragma unroll
        for (int i = 0; i < 8; ++i) s += v[i];
    } else {
#pragma unroll
        for (int i = 0; i < 8; ++i) {
            int idx = base + i;
            v[i] = (idx < SCAN_TOT) ? cnt2[idx] : 0u;
            s += v[i];
        }
    }
    lds[t] = s;
    __syncthreads();
    for (int off = 1; off < 256; off <<= 1) {
        unsigned w = (t >= off) ? lds[t - off] : 0u;
        __syncthreads();
        lds[t] += w;
        __syncthreads();
    }
    unsigned run = lds[t] - s;
#pragma unroll
    for (int i = 0; i < 8; ++i) {
        int idx = base + i;
        if (idx < SCAN_TOT) offs[idx] = run;
        run += v[i];
    }
    if (t == 255) chunkSum[b] = lds[255];
}

// ---------------- K2b: scan the 98 chunk sums ----------------
__global__ __launch_bounds__(128) void k_scan_chunks(
    const unsigned* __restrict__ chunkSum, unsigned* __restrict__ chunkOff) {
    __shared__ unsigned lds[128];
    const int t = threadIdx.x;
    unsigned v = (t < NCH) ? chunkSum[t] : 0u;
    lds[t] = v;
    __syncthreads();
    for (int off = 1; off < 128; off <<= 1) {
        unsigned w = (t >= off) ? lds[t - off] : 0u;
        __syncthreads();
        lds[t] += w;
        __syncthreads();
    }
    if (t < NCH) chunkOff[t] = lds[t] - v;
}

// ---------------- K2c: apply chunk offsets ----------------
__global__ __launch_bounds__(256) void k_scan_apply(
    unsigned* __restrict__ offs, const unsigned* __restrict__ chunkOff) {
    int i = blockIdx.x * blockDim.x + threadIdx.x;
    if (i < SCAN_TOT) offs[i] += chunkOff[i / SCAN_CHUNK];
}

// ---------------- K3: fill CSR (src only; offs becomes segment END) ---------
__global__ __launch_bounds__(256) void k_fill(
    const int* __restrict__ wsrc, const int* __restrict__ wdst,
    const int* __restrict__ csrc, const int* __restrict__ cdst,
    unsigned* __restrict__ offs, int* __restrict__ idx_src) {
    int t = blockIdx.x * blockDim.x + threadIdx.x;
    if (t < E_W) {
        int d = wdst[t];
        unsigned p = atomicAdd(&offs[d], 1u);
        idx_src[p] = wsrc[t];
    }
    if (t < E_C) {
        int d = cdst[t];
        unsigned p = atomicAdd(&offs[N_P + d], 1u);
        idx_src[p] = csrc[t];
    }
}

// ---------------- K4: transform-first GEMVs ----------------
// ht_a  = (h_author @ Wra^T) * outdeg_a^-1/2        [N_A,64]
// ht_pc = (h_paper  @ Wrp^T) * outdeg_p^-1/2        [N_P,64]
// hl    =  h_paper  @ Wl^T + bl                     [N_P,64]
__global__ __launch_bounds__(256) void k_transform(
    const float* __restrict__ h_author, const float* __restrict__ h_paper,
    const float* __restrict__ Wra, const float* __restrict__ Wrp,
    const float* __restrict__ Wl, const float* __restrict__ bl,
    const unsigned* __restrict__ deg_a, const unsigned* __restrict__ deg_p,
    float* __restrict__ ht_a, float* __restrict__ ht_pc,
    float* __restrict__ hl_b) {
    const int lane = threadIdx.x & 63;
    const int wib = threadIdx.x >> 6;
    const int b = blockIdx.x;
    int seg, nrows, nwaves, wave;
    const float* W;
    const float* X;
    float* O;
    if (b < 192)      { seg = 0; W = Wra; X = h_author; O = ht_a;  nrows = N_A; nwaves = 192 * 4; wave = b * 4 + wib; }
    else if (b < 576) { seg = 1; W = Wrp; X = h_paper;  O = ht_pc; nrows = N_P; nwaves = 384 * 4; wave = (b - 192) * 4 + wib; }
    else              { seg = 2; W = Wl;  X = h_paper;  O = hl_b;  nrows = N_P; nwaves = 448 * 4; wave = (b - 576) * 4 + wib; }

    float wrow[DD];
#pragma unroll
    for (int k = 0; k < DD; ++k) wrow[k] = W[(size_t)lane * DD + k];
    const float bias = (seg == 2) ? bl[lane] : 0.f;

    for (int r = wave; r < nrows; r += nwaves) {
        const int ur = __builtin_amdgcn_readfirstlane(r);
        const float* x = X + (size_t)ur * DD;
        float acc = 0.f;
#pragma unroll
        for (int k = 0; k < DD; ++k) acc = fmaf(x[k], wrow[k], acc);
        float outv;
        if (seg == 0)      outv = acc * rsqrtf(fmaxf((float)deg_a[ur], 1.f));
        else if (seg == 1) outv = acc * rsqrtf(fmaxf((float)deg_p[ur], 1.f));
        else               outv = acc + bias;
        O[(size_t)ur * DD + lane] = outv;
    }
}

// ---------------- K5: fused CSR pull-aggregate + elu + softmax -> att rows ---
// One wave per paper node; lane = feature. Writes only the two per-node
// attention rows (51 MB total, sequential). att_w ALIASES hl_b: each row is
// read only by its owning wave before being overwritten -> race-free.
__global__ __launch_bounds__(256) void k_node_agg(
    const float* __restrict__ ht_a, const float* __restrict__ ht_pc,
    const unsigned* __restrict__ cnt2, const unsigned* __restrict__ fin,
    const int* __restrict__ idx_src,
    float* __restrict__ att_w /* == hl_b */, float* __restrict__ att_c,
    const float* __restrict__ bra, const float* __restrict__ brp) {
    const int lane = threadIdx.x & 63;
    const int n = __builtin_amdgcn_readfirstlane(blockIdx.x * 4 + (threadIdx.x >> 6));
    if (n >= N_P) return;
    const int cw = (int)cnt2[n];
    const int cc = (int)cnt2[N_P + n];
    if ((cw | cc) == 0) return;  // isolated node: rows never read downstream
    const int ow = (int)fin[n] - cw;          // fin = end after k_fill
    const int oc = (int)fin[N_P + n] - cc;

    const float hlv = att_w[(size_t)n * DD + lane];  // hl row (before overwrite)

    float accw = 0.f;
    {
        int j = 0;
        for (; j + 4 <= cw; j += 4) {
            int s0 = idx_src[ow + j], s1 = idx_src[ow + j + 1];
            int s2 = idx_src[ow + j + 2], s3 = idx_src[ow + j + 3];
            float v0 = ht_a[(size_t)s0 * DD + lane];
            float v1 = ht_a[(size_t)s1 * DD + lane];
            float v2 = ht_a[(size_t)s2 * DD + lane];
            float v3 = ht_a[(size_t)s3 * DD + lane];
            accw += (v0 + v1) + (v2 + v3);
        }
        for (; j < cw; ++j) accw += ht_a[(size_t)idx_src[ow + j] * DD + lane];
    }
    float accc = 0.f;
    {
        int j = 0;
        for (; j + 4 <= cc; j += 4) {
            int s0 = idx_src[oc + j], s1 = idx_src[oc + j + 1];
            int s2 = idx_src[oc + j + 2], s3 = idx_src[oc + j + 3];
            float v0 = ht_pc[(size_t)s0 * DD + lane];
            float v1 = ht_pc[(size_t)s1 * DD + lane];
            float v2 = ht_pc[(size_t)s2 * DD + lane];
            float v3 = ht_pc[(size_t)s3 * DD + lane];
            accc += (v0 + v1) + (v2 + v3);
        }
        for (; j < cc; ++j) accc += ht_pc[(size_t)idx_src[oc + j] * DD + lane];
    }

    const float cwf = (float)cw, ccf = (float)cc;
    const float hrw = accw * rsqrtf(fmaxf(cwf, 1.f)) + bra[lane];
    const float hrc = accc * rsqrtf(fmaxf(ccf, 1.f)) + brp[lane];
    const float xw = hlv + hrw;
    const float xc = hlv + hrc;
    const float eaw = (xw > 0.f) ? xw : expm1f(xw);  // elu
    const float eac = (xc > 0.f) ? xc : expm1f(xc);

    float aw, ac;
    if (cw > 0 && cc > 0) {
        float m = fmaxf(eaw, eac);
        float ew = __expf(eaw - m);
        float ec = __expf(eac - m);
        float z = cwf * ew + ccf * ec;
        aw = ew / z;
        ac = ec / z;
    } else if (cw > 0) {
        aw = 1.f / cwf; ac = 0.f;
    } else {
        ac = 1.f / ccf; aw = 0.f;
    }

    att_w[(size_t)n * DD + lane] = aw;
    att_c[(size_t)n * DD + lane] = ac;
}

// ---------------- K6: edge-order broadcast of att rows (sequential 512 MB) --
__global__ __launch_bounds__(256) void k_gather(
    const int* __restrict__ wdst, const int* __restrict__ cdst,
    const u32x4* __restrict__ attw4, const u32x4* __restrict__ attc4,
    u32x4* __restrict__ out4) {
    const long long t = (long long)blockIdx.x * blockDim.x + threadIdx.x;
    const long long nw = (long long)E_W * 16;  // 16B chunks in writes portion
    if (t < nw) {
        int e = (int)(t >> 4), p = (int)(t & 15);
        int d = wdst[e];
        u32x4 v = attw4[(size_t)d * 16 + p];
        __builtin_nontemporal_store(v, &out4[t]);
    } else {
        long long u = t - nw;
        if (u < (long long)E_C * 16) {
            int e = (int)(u >> 4), p = (int)(u & 15);
            int d = cdst[e];
            u32x4 v = attc4[(size_t)d * 16 + p];
            __builtin_nontemporal_store(v, &out4[t]);
        }
    }
}

extern "C" void kernel_launch(void* const* d_in, const int* in_sizes, int n_in,
                              void* d_out, int out_size, void* d_ws, size_t ws_size,
                              hipStream_t stream) {
    const float* h_paper  = (const float*)d_in[0];
    const float* h_author = (const float*)d_in[1];
    const float* Wl  = (const float*)d_in[2];
    const float* bl  = (const float*)d_in[3];
    const float* Wra = (const float*)d_in[4];
    const float* bra = (const float*)d_in[5];
    const float* Wrp = (const float*)d_in[6];
    const float* brp = (const float*)d_in[7];
    const int* wsrc = (const int*)d_in[8];
    const int* wdst = (const int*)d_in[9];
    const int* csrc = (const int*)d_in[10];
    const int* cdst = (const int*)d_in[11];

    // workspace layout (~100 MB)
    float* ht_a   = (float*)d_ws;                      // N_A*64
    float* ht_pc  = ht_a + (size_t)N_A * DD;           // N_P*64
    float* hl_att = ht_pc + (size_t)N_P * DD;          // N_P*64 (hl, then att_w)
    float* att_c  = hl_att + (size_t)N_P * DD;         // N_P*64
    int* idx_src  = (int*)(att_c + (size_t)N_P * DD);  // E_TOT
    unsigned* deg_a = (unsigned*)(idx_src + E_TOT);    // N_A   (zeroed)
    unsigned* deg_p = deg_a + N_A;                     // N_P   (zeroed)
    unsigned* cnt2  = deg_p + N_P;                     // 2*N_P (zeroed)
    unsigned* offs  = cnt2 + SCAN_TOT;                 // 2*N_P
    unsigned* chunkSum = offs + SCAN_TOT;              // 128
    unsigned* chunkOff = chunkSum + 128;               // 128

    (void)hipMemsetAsync(deg_a, 0, (size_t)(N_A + N_P + SCAN_TOT) * sizeof(unsigned), stream);

    const int thr = 256;
    // K1: degrees + per-relation in-degree counts (2 edges/thread)
    k_degrees<<<(E_C / 2 + thr - 1) / thr, thr, 0, stream>>>(wsrc, wdst, csrc, cdst,
                                                             deg_a, deg_p, cnt2);
    // K2: exclusive scan of concatenated counts -> CSR offsets
    k_scan_local<<<NCH, 256, 0, stream>>>(cnt2, offs, chunkSum);
    k_scan_chunks<<<1, 128, 0, stream>>>(chunkSum, chunkOff);
    k_scan_apply<<<(SCAN_TOT + 255) / 256, 256, 0, stream>>>(offs, chunkOff);
    // K3: scatter src ids into CSR slots (offs -> segment ends)
    k_fill<<<(E_C + thr - 1) / thr, thr, 0, stream>>>(wsrc, wdst, csrc, cdst,
                                                      offs, idx_src);
    // K4: transform-first GEMVs (3 segments in one launch)
    k_transform<<<1024, 256, 0, stream>>>(h_author, h_paper, Wra, Wrp, Wl, bl,
                                          deg_a, deg_p, ht_a, ht_pc, hl_att);
    // K5: fused pull-aggregate + softmax -> per-node att rows (att_w aliases hl)
    k_node_agg<<<(N_P + 3) / 4, 256, 0, stream>>>(ht_a, ht_pc, cnt2, offs, idx_src,
                                                  hl_att, att_c, bra, brp);
    // K6: edge-order broadcast, fully sequential nontemporal output write
    {
        long long total = ((long long)E_W + E_C) * 16;
        k_gather<<<(int)((total + 255) / 256), 256, 0, stream>>>(
            wdst, cdst, (const u32x4*)hl_att, (const u32x4*)att_c, (u32x4*)d_out);
    }
}

// Round 4
// 1003.251 us; speedup vs baseline: 1.0687x; 1.0687x over previous
//
#include <hip/hip_runtime.h>

#define N_P 100000
#define N_A 50000
#define DD  64
#define E_W 800000
#define E_C 1200000
#define E_TOT (E_W + E_C)

#define SCAN_TOT (2 * N_P)
#define SCAN_CHUNK 2048
#define NCH ((SCAN_TOT + SCAN_CHUNK - 1) / SCAN_CHUNK)  // 98

// ---------------- K1: degree histograms (int atomics, int4 index loads) ------
__global__ __launch_bounds__(256) void k_degrees(
    const int* __restrict__ wsrc, const int* __restrict__ wdst,
    const int* __restrict__ csrc, const int* __restrict__ cdst,
    unsigned* __restrict__ deg_a, unsigned* __restrict__ deg_p,
    unsigned* __restrict__ cnt2) {
    int t = blockIdx.x * blockDim.x + threadIdx.x;
    int e = t * 4;
    if (e + 4 <= E_W) {  // E_W % 4 == 0
        int4 s = *reinterpret_cast<const int4*>(&wsrc[e]);
        int4 d = *reinterpret_cast<const int4*>(&wdst[e]);
        atomicAdd(&deg_a[s.x], 1u); atomicAdd(&deg_a[s.y], 1u);
        atomicAdd(&deg_a[s.z], 1u); atomicAdd(&deg_a[s.w], 1u);
        atomicAdd(&cnt2[d.x], 1u);  atomicAdd(&cnt2[d.y], 1u);
        atomicAdd(&cnt2[d.z], 1u);  atomicAdd(&cnt2[d.w], 1u);
    }
    if (e + 4 <= E_C) {  // E_C % 4 == 0
        int4 s = *reinterpret_cast<const int4*>(&csrc[e]);
        int4 d = *reinterpret_cast<const int4*>(&cdst[e]);
        atomicAdd(&deg_p[s.x], 1u); atomicAdd(&deg_p[s.y], 1u);
        atomicAdd(&deg_p[s.z], 1u); atomicAdd(&deg_p[s.w], 1u);
        atomicAdd(&cnt2[N_P + d.x], 1u); atomicAdd(&cnt2[N_P + d.y], 1u);
        atomicAdd(&cnt2[N_P + d.z], 1u); atomicAdd(&cnt2[N_P + d.w], 1u);
    }
}

// ---------------- K2a: per-chunk local exclusive scan ----------------
__global__ __launch_bounds__(256) void k_scan_local(
    const unsigned* __restrict__ cnt2, unsigned* __restrict__ offs,
    unsigned* __restrict__ chunkSum) {
    __shared__ unsigned lds[256];
    const int b = blockIdx.x, t = threadIdx.x;
    const int base = b * SCAN_CHUNK + t * 8;
    unsigned v[8];
    unsigned s = 0;
    if (base + 8 <= SCAN_TOT) {
        uint4 a0 = *reinterpret_cast<const uint4*>(&cnt2[base]);
        uint4 a1 = *reinterpret_cast<const uint4*>(&cnt2[base + 4]);
        v[0] = a0.x; v[1] = a0.y; v[2] = a0.z; v[3] = a0.w;
        v[4] = a1.x; v[5] = a1.y; v[6] = a1.z; v[7] = a1.w;
#pragma unroll
        for (int i = 0; i < 8; ++i) s += v[i];
    } else {
#pragma unroll
        for (int i = 0; i < 8; ++i) {
            int idx = base + i;
            v[i] = (idx < SCAN_TOT) ? cnt2[idx] : 0u;
            s += v[i];
        }
    }
    lds[t] = s;
    __syncthreads();
    for (int off = 1; off < 256; off <<= 1) {
        unsigned w = (t >= off) ? lds[t - off] : 0u;
        __syncthreads();
        lds[t] += w;
        __syncthreads();
    }
    unsigned run = lds[t] - s;
#pragma unroll
    for (int i = 0; i < 8; ++i) {
        int idx = base + i;
        if (idx < SCAN_TOT) offs[idx] = run;
        run += v[i];
    }
    if (t == 255) chunkSum[b] = lds[255];
}

// ---------------- K2b: scan the 98 chunk sums ----------------
__global__ __launch_bounds__(128) void k_scan_chunks(
    const unsigned* __restrict__ chunkSum, unsigned* __restrict__ chunkOff) {
    __shared__ unsigned lds[128];
    const int t = threadIdx.x;
    unsigned v = (t < NCH) ? chunkSum[t] : 0u;
    lds[t] = v;
    __syncthreads();
    for (int off = 1; off < 128; off <<= 1) {
        unsigned w = (t >= off) ? lds[t - off] : 0u;
        __syncthreads();
        lds[t] += w;
        __syncthreads();
    }
    if (t < NCH) chunkOff[t] = lds[t] - v;
}

// ---------------- K2c: apply chunk offsets ----------------
__global__ __launch_bounds__(256) void k_scan_apply(
    unsigned* __restrict__ offs, const unsigned* __restrict__ chunkOff) {
    int i = blockIdx.x * blockDim.x + threadIdx.x;
    if (i < SCAN_TOT) offs[i] += chunkOff[i / SCAN_CHUNK];
}

// ---------------- K3: fill CSR with int2{src,eid} (offs -> segment END) ------
__global__ __launch_bounds__(256) void k_fill(
    const int* __restrict__ wsrc, const int* __restrict__ wdst,
    const int* __restrict__ csrc, const int* __restrict__ cdst,
    unsigned* __restrict__ offs, int2* __restrict__ idx2) {
    int t = blockIdx.x * blockDim.x + threadIdx.x;
    int e = t * 2;
    if (e + 2 <= E_W) {  // E_W % 2 == 0
        int2 s = *reinterpret_cast<const int2*>(&wsrc[e]);
        int2 d = *reinterpret_cast<const int2*>(&wdst[e]);
        unsigned p0 = atomicAdd(&offs[d.x], 1u);
        idx2[p0] = make_int2(s.x, e);
        unsigned p1 = atomicAdd(&offs[d.y], 1u);
        idx2[p1] = make_int2(s.y, e + 1);
    }
    if (e + 2 <= E_C) {  // E_C % 2 == 0
        int2 s = *reinterpret_cast<const int2*>(&csrc[e]);
        int2 d = *reinterpret_cast<const int2*>(&cdst[e]);
        unsigned p0 = atomicAdd(&offs[N_P + d.x], 1u);
        idx2[p0] = make_int2(s.x, e);
        unsigned p1 = atomicAdd(&offs[N_P + d.y], 1u);
        idx2[p1] = make_int2(s.y, e + 1);
    }
}

// ---------------- K4: transform-first GEMVs ----------------
// ht_a  = (h_author @ Wra^T) * outdeg_a^-1/2        [N_A,64]
// ht_pc = (h_paper  @ Wrp^T) * outdeg_p^-1/2        [N_P,64]
// hl    =  h_paper  @ Wl^T + bl                     [N_P,64]
__global__ __launch_bounds__(256) void k_transform(
    const float* __restrict__ h_author, const float* __restrict__ h_paper,
    const float* __restrict__ Wra, const float* __restrict__ Wrp,
    const float* __restrict__ Wl, const float* __restrict__ bl,
    const unsigned* __restrict__ deg_a, const unsigned* __restrict__ deg_p,
    float* __restrict__ ht_a, float* __restrict__ ht_pc,
    float* __restrict__ hl_b) {
    const int lane = threadIdx.x & 63;
    const int wib = threadIdx.x >> 6;
    const int b = blockIdx.x;
    int seg, nrows, nwaves, wave;
    const float* W;
    const float* X;
    float* O;
    if (b < 192)      { seg = 0; W = Wra; X = h_author; O = ht_a;  nrows = N_A; nwaves = 192 * 4; wave = b * 4 + wib; }
    else if (b < 576) { seg = 1; W = Wrp; X = h_paper;  O = ht_pc; nrows = N_P; nwaves = 384 * 4; wave = (b - 192) * 4 + wib; }
    else              { seg = 2; W = Wl;  X = h_paper;  O = hl_b;  nrows = N_P; nwaves = 448 * 4; wave = (b - 576) * 4 + wib; }

    float wrow[DD];
#pragma unroll
    for (int k = 0; k < DD; ++k) wrow[k] = W[(size_t)lane * DD + k];
    const float bias = (seg == 2) ? bl[lane] : 0.f;

    for (int r = wave; r < nrows; r += nwaves) {
        const int ur = __builtin_amdgcn_readfirstlane(r);
        const float* x = X + (size_t)ur * DD;
        float acc = 0.f;
#pragma unroll
        for (int k = 0; k < DD; ++k) acc = fmaf(x[k], wrow[k], acc);
        float outv;
        if (seg == 0)      outv = acc * rsqrtf(fmaxf((float)deg_a[ur], 1.f));
        else if (seg == 1) outv = acc * rsqrtf(fmaxf((float)deg_p[ur], 1.f));
        else               outv = acc + bias;
        O[(size_t)ur * DD + lane] = outv;
    }
}

// ---------------- K5: fused pull-aggregate + elu + softmax + direct edge write
// One wave per paper node; lane = feature. Gathers transformed neighbor rows
// (L2/L3-hot), computes the 2-point hetero softmax, writes attention rows
// straight to the per-edge output (nontemporal: no reuse, don't pollute L2).
__global__ __launch_bounds__(256) void k_node_agg(
    const float* __restrict__ ht_a, const float* __restrict__ ht_pc,
    const float* __restrict__ hl_b,
    const unsigned* __restrict__ cnt2, const unsigned* __restrict__ fin,
    const int2* __restrict__ idx2,
    const float* __restrict__ bra, const float* __restrict__ brp,
    float* __restrict__ out) {
    const int lane = threadIdx.x & 63;
    const int n = __builtin_amdgcn_readfirstlane(blockIdx.x * 4 + (threadIdx.x >> 6));
    if (n >= N_P) return;
    const int cw = (int)cnt2[n];
    const int cc = (int)cnt2[N_P + n];
    if ((cw | cc) == 0) return;  // isolated node: owns no output rows
    const int ow = (int)fin[n] - cw;          // fin = segment end after k_fill
    const int oc = (int)fin[N_P + n] - cc;

    const float hlv = hl_b[(size_t)n * DD + lane];

    float accw = 0.f;
    {
        int j = 0;
        for (; j + 4 <= cw; j += 4) {
            int s0 = idx2[ow + j].x,     s1 = idx2[ow + j + 1].x;
            int s2 = idx2[ow + j + 2].x, s3 = idx2[ow + j + 3].x;
            float v0 = ht_a[(size_t)s0 * DD + lane];
            float v1 = ht_a[(size_t)s1 * DD + lane];
            float v2 = ht_a[(size_t)s2 * DD + lane];
            float v3 = ht_a[(size_t)s3 * DD + lane];
            accw += (v0 + v1) + (v2 + v3);
        }
        for (; j < cw; ++j) accw += ht_a[(size_t)idx2[ow + j].x * DD + lane];
    }
    float accc = 0.f;
    {
        int j = 0;
        for (; j + 4 <= cc; j += 4) {
            int s0 = idx2[oc + j].x,     s1 = idx2[oc + j + 1].x;
            int s2 = idx2[oc + j + 2].x, s3 = idx2[oc + j + 3].x;
            float v0 = ht_pc[(size_t)s0 * DD + lane];
            float v1 = ht_pc[(size_t)s1 * DD + lane];
            float v2 = ht_pc[(size_t)s2 * DD + lane];
            float v3 = ht_pc[(size_t)s3 * DD + lane];
            accc += (v0 + v1) + (v2 + v3);
        }
        for (; j < cc; ++j) accc += ht_pc[(size_t)idx2[oc + j].x * DD + lane];
    }

    const float cwf = (float)cw, ccf = (float)cc;
    const float hrw = accw * rsqrtf(fmaxf(cwf, 1.f)) + bra[lane];
    const float hrc = accc * rsqrtf(fmaxf(ccf, 1.f)) + brp[lane];
    const float xw = hlv + hrw;
    const float xc = hlv + hrc;
    const float eaw = (xw > 0.f) ? xw : expm1f(xw);  // elu
    const float eac = (xc > 0.f) ? xc : expm1f(xc);

    float aw, ac;
    if (cw > 0 && cc > 0) {
        float m = fmaxf(eaw, eac);
        float ew = __expf(eaw - m);
        float ec = __expf(eac - m);
        float z = cwf * ew + ccf * ec;
        aw = ew / z;
        ac = ec / z;
    } else if (cw > 0) {
        aw = 1.f / cwf; ac = 0.f;
    } else {
        ac = 1.f / ccf; aw = 0.f;
    }

    for (int j = 0; j < cw; ++j) {
        int e = idx2[ow + j].y;
        __builtin_nontemporal_store(aw, &out[(size_t)e * DD + lane]);
    }
    for (int j = 0; j < cc; ++j) {
        int e = idx2[oc + j].y;
        __builtin_nontemporal_store(ac, &out[((size_t)(E_W + e)) * DD + lane]);
    }
}

extern "C" void kernel_launch(void* const* d_in, const int* in_sizes, int n_in,
                              void* d_out, int out_size, void* d_ws, size_t ws_size,
                              hipStream_t stream) {
    const float* h_paper  = (const float*)d_in[0];
    const float* h_author = (const float*)d_in[1];
    const float* Wl  = (const float*)d_in[2];
    const float* bl  = (const float*)d_in[3];
    const float* Wra = (const float*)d_in[4];
    const float* bra = (const float*)d_in[5];
    const float* Wrp = (const float*)d_in[6];
    const float* brp = (const float*)d_in[7];
    const int* wsrc = (const int*)d_in[8];
    const int* wdst = (const int*)d_in[9];
    const int* csrc = (const int*)d_in[10];
    const int* cdst = (const int*)d_in[11];

    // workspace layout (~93 MB)
    float* ht_a  = (float*)d_ws;                      // N_A*64
    float* ht_pc = ht_a + (size_t)N_A * DD;           // N_P*64
    float* hl_b  = ht_pc + (size_t)N_P * DD;          // N_P*64
    int2* idx2   = (int2*)(hl_b + (size_t)N_P * DD);  // E_TOT int2
    unsigned* deg_a = (unsigned*)(idx2 + E_TOT);      // N_A   (zeroed)
    unsigned* deg_p = deg_a + N_A;                    // N_P   (zeroed)
    unsigned* cnt2  = deg_p + N_P;                    // 2*N_P (zeroed)
    unsigned* offs  = cnt2 + SCAN_TOT;                // 2*N_P
    unsigned* chunkSum = offs + SCAN_TOT;             // 128
    unsigned* chunkOff = chunkSum + 128;              // 128

    (void)hipMemsetAsync(deg_a, 0, (size_t)(N_A + N_P + SCAN_TOT) * sizeof(unsigned), stream);

    // K1: degrees + per-relation in-degree counts (4 edges/thread)
    k_degrees<<<(E_C / 4 + 255) / 256, 256, 0, stream>>>(wsrc, wdst, csrc, cdst,
                                                         deg_a, deg_p, cnt2);
    // K2: exclusive scan of concatenated counts -> CSR offsets
    k_scan_local<<<NCH, 256, 0, stream>>>(cnt2, offs, chunkSum);
    k_scan_chunks<<<1, 128, 0, stream>>>(chunkSum, chunkOff);
    k_scan_apply<<<(SCAN_TOT + 255) / 256, 256, 0, stream>>>(offs, chunkOff);
    // K3: scatter {src,eid} pairs into CSR slots (one 8B store per edge)
    k_fill<<<(E_C / 2 + 255) / 256, 256, 0, stream>>>(wsrc, wdst, csrc, cdst,
                                                      offs, idx2);
    // K4: transform-first GEMVs (3 segments in one launch)
    k_transform<<<1024, 256, 0, stream>>>(h_author, h_paper, Wra, Wrp, Wl, bl,
                                          deg_a, deg_p, ht_a, ht_pc, hl_b);
    // K5: fused pull-aggregate + softmax + direct per-edge output write
    k_node_agg<<<(N_P + 3) / 4, 256, 0, stream>>>(ht_a, ht_pc, hl_b, cnt2, offs,
                                                  idx2, bra, brp, (float*)d_out);
}

// Round 5
// 995.362 us; speedup vs baseline: 1.0772x; 1.0079x over previous
//
#include <hip/hip_runtime.h>

#define N_P 100000
#define N_A 50000
#define DD  64
#define E_W 800000
#define E_C 1200000
#define E_TOT (E_W + E_C)

#define SCAN_TOT (2 * N_P)
#define SCAN_CHUNK 2048
#define NCH ((SCAN_TOT + SCAN_CHUNK - 1) / SCAN_CHUNK)  // 98

#define HIST_BLOCKS 1172   // ceil(E_C/4/256)
#define GEMV_BLOCKS 1024   // 192 (Wra) + 384 (Wrp) + 448 (Wl)
#define KA_BLOCKS (HIST_BLOCKS + GEMV_BLOCKS)

typedef float f32x4 __attribute__((ext_vector_type(4)));

// ---------------- KA: fused degree histograms + unscaled GEMVs --------------
// Blocks [0,HIST_BLOCKS): int atomics histogram (4 edges/thread, int4 loads).
// Blocks [HIST_BLOCKS,..): the three 64x64 GEMVs (one W row per lane in VGPRs).
// These two phases share no data -> co-resident waves overlap atomic latency
// with VALU work. ht rows are written UNSCALED; rsqrt(out-deg) is applied
// per-edge in K5 (linearity).
__global__ __launch_bounds__(256) void k_hist_gemv(
    const int* __restrict__ wsrc, const int* __restrict__ wdst,
    const int* __restrict__ csrc, const int* __restrict__ cdst,
    unsigned* __restrict__ deg_a, unsigned* __restrict__ deg_p,
    unsigned* __restrict__ cnt2,
    const float* __restrict__ h_author, const float* __restrict__ h_paper,
    const float* __restrict__ Wra, const float* __restrict__ Wrp,
    const float* __restrict__ Wl, const float* __restrict__ bl,
    float* __restrict__ ht_a, float* __restrict__ ht_pc,
    float* __restrict__ hl_b) {
    const int b = blockIdx.x;
    if (b < HIST_BLOCKS) {
        int t = b * 256 + threadIdx.x;
        int e = t * 4;
        if (e + 4 <= E_W) {  // E_W % 4 == 0
            int4 s = *reinterpret_cast<const int4*>(&wsrc[e]);
            int4 d = *reinterpret_cast<const int4*>(&wdst[e]);
            atomicAdd(&deg_a[s.x], 1u); atomicAdd(&deg_a[s.y], 1u);
            atomicAdd(&deg_a[s.z], 1u); atomicAdd(&deg_a[s.w], 1u);
            atomicAdd(&cnt2[d.x], 1u);  atomicAdd(&cnt2[d.y], 1u);
            atomicAdd(&cnt2[d.z], 1u);  atomicAdd(&cnt2[d.w], 1u);
        }
        if (e + 4 <= E_C) {  // E_C % 4 == 0
            int4 s = *reinterpret_cast<const int4*>(&csrc[e]);
            int4 d = *reinterpret_cast<const int4*>(&cdst[e]);
            atomicAdd(&deg_p[s.x], 1u); atomicAdd(&deg_p[s.y], 1u);
            atomicAdd(&deg_p[s.z], 1u); atomicAdd(&deg_p[s.w], 1u);
            atomicAdd(&cnt2[N_P + d.x], 1u); atomicAdd(&cnt2[N_P + d.y], 1u);
            atomicAdd(&cnt2[N_P + d.z], 1u); atomicAdd(&cnt2[N_P + d.w], 1u);
        }
        return;
    }
    // ---- GEMV part ----
    const int gb = b - HIST_BLOCKS;
    const int lane = threadIdx.x & 63;
    const int wib = threadIdx.x >> 6;
    int seg, nrows, nwaves, wave;
    const float* W;
    const float* X;
    float* O;
    if (gb < 192)      { seg = 0; W = Wra; X = h_author; O = ht_a;  nrows = N_A; nwaves = 192 * 4; wave = gb * 4 + wib; }
    else if (gb < 576) { seg = 1; W = Wrp; X = h_paper;  O = ht_pc; nrows = N_P; nwaves = 384 * 4; wave = (gb - 192) * 4 + wib; }
    else               { seg = 2; W = Wl;  X = h_paper;  O = hl_b;  nrows = N_P; nwaves = 448 * 4; wave = (gb - 576) * 4 + wib; }

    float wrow[DD];
#pragma unroll
    for (int k = 0; k < DD; ++k) wrow[k] = W[(size_t)lane * DD + k];
    const float bias = (seg == 2) ? bl[lane] : 0.f;

    for (int r = wave; r < nrows; r += nwaves) {
        const int ur = __builtin_amdgcn_readfirstlane(r);
        const float* x = X + (size_t)ur * DD;
        float acc = 0.f;
#pragma unroll
        for (int k = 0; k < DD; ++k) acc = fmaf(x[k], wrow[k], acc);
        O[(size_t)ur * DD + lane] = (seg == 2) ? (acc + bias) : acc;
    }
}

// ---------------- K2a: per-chunk local exclusive scan ----------------
__global__ __launch_bounds__(256) void k_scan_local(
    const unsigned* __restrict__ cnt2, unsigned* __restrict__ offs,
    unsigned* __restrict__ chunkSum) {
    __shared__ unsigned lds[256];
    const int b = blockIdx.x, t = threadIdx.x;
    const int base = b * SCAN_CHUNK + t * 8;
    unsigned v[8];
    unsigned s = 0;
    if (base + 8 <= SCAN_TOT) {
        uint4 a0 = *reinterpret_cast<const uint4*>(&cnt2[base]);
        uint4 a1 = *reinterpret_cast<const uint4*>(&cnt2[base + 4]);
        v[0] = a0.x; v[1] = a0.y; v[2] = a0.z; v[3] = a0.w;
        v[4] = a1.x; v[5] = a1.y; v[6] = a1.z; v[7] = a1.w;
#pragma unroll
        for (int i = 0; i < 8; ++i) s += v[i];
    } else {
#pragma unroll
        for (int i = 0; i < 8; ++i) {
            int idx = base + i;
            v[i] = (idx < SCAN_TOT) ? cnt2[idx] : 0u;
            s += v[i];
        }
    }
    lds[t] = s;
    __syncthreads();
    for (int off = 1; off < 256; off <<= 1) {
        unsigned w = (t >= off) ? lds[t - off] : 0u;
        __syncthreads();
        lds[t] += w;
        __syncthreads();
    }
    unsigned run = lds[t] - s;
#pragma unroll
    for (int i = 0; i < 8; ++i) {
        int idx = base + i;
        if (idx < SCAN_TOT) offs[idx] = run;
        run += v[i];
    }
    if (t == 255) chunkSum[b] = lds[255];
}

// ---------------- K2b: scan the 98 chunk sums ----------------
__global__ __launch_bounds__(128) void k_scan_chunks(
    const unsigned* __restrict__ chunkSum, unsigned* __restrict__ chunkOff) {
    __shared__ unsigned lds[128];
    const int t = threadIdx.x;
    unsigned v = (t < NCH) ? chunkSum[t] : 0u;
    lds[t] = v;
    __syncthreads();
    for (int off = 1; off < 128; off <<= 1) {
        unsigned w = (t >= off) ? lds[t - off] : 0u;
        __syncthreads();
        lds[t] += w;
        __syncthreads();
    }
    if (t < NCH) chunkOff[t] = lds[t] - v;
}

// ---------------- K2c: apply chunk offsets + precompute rsqrt(out-deg) ------
__global__ __launch_bounds__(256) void k_scan_apply(
    unsigned* __restrict__ offs, const unsigned* __restrict__ chunkOff,
    const unsigned* __restrict__ deg_a, const unsigned* __restrict__ deg_p,
    float* __restrict__ rdeg_a, float* __restrict__ rdeg_p) {
    int i = blockIdx.x * blockDim.x + threadIdx.x;
    if (i < SCAN_TOT) offs[i] += chunkOff[i / SCAN_CHUNK];
    if (i < N_A) rdeg_a[i] = rsqrtf(fmaxf((float)deg_a[i], 1.f));
    if (i < N_P) rdeg_p[i] = rsqrtf(fmaxf((float)deg_p[i], 1.f));
}

// ---------------- K3: fill CSR with int2{src,eid} (offs -> segment END) ------
__global__ __launch_bounds__(256) void k_fill(
    const int* __restrict__ wsrc, const int* __restrict__ wdst,
    const int* __restrict__ csrc, const int* __restrict__ cdst,
    unsigned* __restrict__ offs, int2* __restrict__ idx2) {
    int t = blockIdx.x * blockDim.x + threadIdx.x;
    int e = t * 2;
    if (e + 2 <= E_W) {  // E_W % 2 == 0
        int2 s = *reinterpret_cast<const int2*>(&wsrc[e]);
        int2 d = *reinterpret_cast<const int2*>(&wdst[e]);
        unsigned p0 = atomicAdd(&offs[d.x], 1u);
        idx2[p0] = make_int2(s.x, e);
        unsigned p1 = atomicAdd(&offs[d.y], 1u);
        idx2[p1] = make_int2(s.y, e + 1);
    }
    if (e + 2 <= E_C) {  // E_C % 2 == 0
        int2 s = *reinterpret_cast<const int2*>(&csrc[e]);
        int2 d = *reinterpret_cast<const int2*>(&cdst[e]);
        unsigned p0 = atomicAdd(&offs[N_P + d.x], 1u);
        idx2[p0] = make_int2(s.x, e);
        unsigned p1 = atomicAdd(&offs[N_P + d.y], 1u);
        idx2[p1] = make_int2(s.y, e + 1);
    }
}

// ---------------- K5: fused pull-aggregate + elu + softmax + packed edge write
// Persistent waves (grid-stride, one node/wave/iter; lane = feature).
// Gathers unscaled ht rows and applies rsqrt(out-deg) per edge as fma.
// Output: row content is uniform per relation -> pack once into float4/lane,
// write 4 rows per dwordx4 store instruction (16B/lane), nontemporal.
__global__ __launch_bounds__(256) void k_node_agg(
    const float* __restrict__ ht_a, const float* __restrict__ ht_pc,
    const float* __restrict__ hl_b,
    const float* __restrict__ rdeg_a, const float* __restrict__ rdeg_p,
    const unsigned* __restrict__ cnt2, const unsigned* __restrict__ fin,
    const int2* __restrict__ idx2,
    const float* __restrict__ bra, const float* __restrict__ brp,
    float* __restrict__ out, int n_waves) {
    const int lane = threadIdx.x & 63;
    const int q = lane & 15;        // 16B-slot within row
    const int sub = lane >> 4;      // which of 4 rows per store group
    const int wave0 = blockIdx.x * 4 + (threadIdx.x >> 6);

    for (int n0 = wave0; n0 < N_P; n0 += n_waves) {
        const int n = __builtin_amdgcn_readfirstlane(n0);
        const int cw = (int)cnt2[n];
        const int cc = (int)cnt2[N_P + n];
        if ((cw | cc) == 0) continue;  // isolated node: owns no output rows
        const int ow = (int)fin[n] - cw;
        const int oc = (int)fin[N_P + n] - cc;

        const float hlv = hl_b[(size_t)n * DD + lane];

        float accw = 0.f;
        {
            int j = 0;
            for (; j + 4 <= cw; j += 4) {
                int s0 = idx2[ow + j].x,     s1 = idx2[ow + j + 1].x;
                int s2 = idx2[ow + j + 2].x, s3 = idx2[ow + j + 3].x;
                float r0 = rdeg_a[s0], r1 = rdeg_a[s1];
                float r2 = rdeg_a[s2], r3 = rdeg_a[s3];
                float v0 = ht_a[(size_t)s0 * DD + lane];
                float v1 = ht_a[(size_t)s1 * DD + lane];
                float v2 = ht_a[(size_t)s2 * DD + lane];
                float v3 = ht_a[(size_t)s3 * DD + lane];
                accw = fmaf(v0, r0, accw);
                accw = fmaf(v1, r1, accw);
                accw = fmaf(v2, r2, accw);
                accw = fmaf(v3, r3, accw);
            }
            for (; j < cw; ++j) {
                int s = idx2[ow + j].x;
                accw = fmaf(ht_a[(size_t)s * DD + lane], rdeg_a[s], accw);
            }
        }
        float accc = 0.f;
        {
            int j = 0;
            for (; j + 4 <= cc; j += 4) {
                int s0 = idx2[oc + j].x,     s1 = idx2[oc + j + 1].x;
                int s2 = idx2[oc + j + 2].x, s3 = idx2[oc + j + 3].x;
                float r0 = rdeg_p[s0], r1 = rdeg_p[s1];
                float r2 = rdeg_p[s2], r3 = rdeg_p[s3];
                float v0 = ht_pc[(size_t)s0 * DD + lane];
                float v1 = ht_pc[(size_t)s1 * DD + lane];
                float v2 = ht_pc[(size_t)s2 * DD + lane];
                float v3 = ht_pc[(size_t)s3 * DD + lane];
                accc = fmaf(v0, r0, accc);
                accc = fmaf(v1, r1, accc);
                accc = fmaf(v2, r2, accc);
                accc = fmaf(v3, r3, accc);
            }
            for (; j < cc; ++j) {
                int s = idx2[oc + j].x;
                accc = fmaf(ht_pc[(size_t)s * DD + lane], rdeg_p[s], accc);
            }
        }

        const float cwf = (float)cw, ccf = (float)cc;
        const float hrw = accw * rsqrtf(fmaxf(cwf, 1.f)) + bra[lane];
        const float hrc = accc * rsqrtf(fmaxf(ccf, 1.f)) + brp[lane];
        const float xw = hlv + hrw;
        const float xc = hlv + hrc;
        const float eaw = (xw > 0.f) ? xw : expm1f(xw);  // elu
        const float eac = (xc > 0.f) ? xc : expm1f(xc);

        float aw, ac;
        if (cw > 0 && cc > 0) {
            float m = fmaxf(eaw, eac);
            float ew = __expf(eaw - m);
            float ec = __expf(eac - m);
            float z = cwf * ew + ccf * ec;
            aw = ew / z;
            ac = ec / z;
        } else if (cw > 0) {
            aw = 1.f / cwf; ac = 0.f;
        } else {
            ac = 1.f / ccf; aw = 0.f;
        }

        // pack: lane l holds features q*4..q*4+3 of the (uniform) row
        f32x4 pw, pc;
        pw.x = __shfl(aw, q * 4 + 0); pw.y = __shfl(aw, q * 4 + 1);
        pw.z = __shfl(aw, q * 4 + 2); pw.w = __shfl(aw, q * 4 + 3);
        pc.x = __shfl(ac, q * 4 + 0); pc.y = __shfl(ac, q * 4 + 1);
        pc.z = __shfl(ac, q * 4 + 2); pc.w = __shfl(ac, q * 4 + 3);

        for (int j = 0; j < cw; j += 4) {
            int r = j + sub;
            int rc = (r < cw) ? r : (cw - 1);
            int e = idx2[ow + rc].y;
            if (r < cw)
                __builtin_nontemporal_store(
                    pw, (f32x4*)(out + (size_t)e * DD + q * 4));
        }
        for (int j = 0; j < cc; j += 4) {
            int r = j + sub;
            int rc = (r < cc) ? r : (cc - 1);
            int e = idx2[oc + rc].y;
            if (r < cc)
                __builtin_nontemporal_store(
                    pc, (f32x4*)(out + ((size_t)(E_W + e)) * DD + q * 4));
        }
    }
}

extern "C" void kernel_launch(void* const* d_in, const int* in_sizes, int n_in,
                              void* d_out, int out_size, void* d_ws, size_t ws_size,
                              hipStream_t stream) {
    const float* h_paper  = (const float*)d_in[0];
    const float* h_author = (const float*)d_in[1];
    const float* Wl  = (const float*)d_in[2];
    const float* bl  = (const float*)d_in[3];
    const float* Wra = (const float*)d_in[4];
    const float* bra = (const float*)d_in[5];
    const float* Wrp = (const float*)d_in[6];
    const float* brp = (const float*)d_in[7];
    const int* wsrc = (const int*)d_in[8];
    const int* wdst = (const int*)d_in[9];
    const int* csrc = (const int*)d_in[10];
    const int* cdst = (const int*)d_in[11];

    // workspace layout (~94 MB)
    float* ht_a  = (float*)d_ws;                      // N_A*64
    float* ht_pc = ht_a + (size_t)N_A * DD;           // N_P*64
    float* hl_b  = ht_pc + (size_t)N_P * DD;          // N_P*64
    int2* idx2   = (int2*)(hl_b + (size_t)N_P * DD);  // E_TOT int2
    unsigned* deg_a = (unsigned*)(idx2 + E_TOT);      // N_A   (zeroed)
    unsigned* deg_p = deg_a + N_A;                    // N_P   (zeroed)
    unsigned* cnt2  = deg_p + N_P;                    // 2*N_P (zeroed)
    unsigned* offs  = cnt2 + SCAN_TOT;                // 2*N_P
    unsigned* chunkSum = offs + SCAN_TOT;             // 128
    unsigned* chunkOff = chunkSum + 128;              // 128
    float* rdeg_a = (float*)(chunkOff + 128);         // N_A
    float* rdeg_p = rdeg_a + N_A;                     // N_P

    (void)hipMemsetAsync(deg_a, 0, (size_t)(N_A + N_P + SCAN_TOT) * sizeof(unsigned), stream);

    // KA: fused histograms (atomic-latency-bound) + GEMVs (VALU-bound)
    k_hist_gemv<<<KA_BLOCKS, 256, 0, stream>>>(
        wsrc, wdst, csrc, cdst, deg_a, deg_p, cnt2,
        h_author, h_paper, Wra, Wrp, Wl, bl, ht_a, ht_pc, hl_b);
    // K2: exclusive scan of concatenated counts -> CSR offsets (+rdeg tables)
    k_scan_local<<<NCH, 256, 0, stream>>>(cnt2, offs, chunkSum);
    k_scan_chunks<<<1, 128, 0, stream>>>(chunkSum, chunkOff);
    k_scan_apply<<<(SCAN_TOT + 255) / 256, 256, 0, stream>>>(
        offs, chunkOff, deg_a, deg_p, rdeg_a, rdeg_p);
    // K3: scatter {src,eid} pairs into CSR slots (one 8B store per edge)
    k_fill<<<(E_C / 2 + 255) / 256, 256, 0, stream>>>(wsrc, wdst, csrc, cdst,
                                                      offs, idx2);
    // K5: persistent-wave pull-aggregate + softmax + packed per-edge writes
    {
        int blocks = 2048;
        int n_waves = blocks * 4;
        k_node_agg<<<blocks, 256, 0, stream>>>(
            ht_a, ht_pc, hl_b, rdeg_a, rdeg_p, cnt2, offs, idx2,
            bra, brp, (float*)d_out, n_waves);
    }
}